// Round 10
// baseline (210.223 us; speedup 1.0000x reference)
//
#include <hip/hip_runtime.h>
#include <hip/hip_fp16.h>

#define IRR    56
#define EF     48
#define WN     832
#define NEDGE  160000
#define NNODE  8000
#define NT     256         // 4 waves
#define EB     128         // edges per block (32 per wave, 2 groups of 16)
#define NBLK   (NEDGE / EB)
#define TPP    13          // n-tiles per pass (52 total, 4 passes)
#define PASS_U4 1664       // uint4 per pass = 26624 B

#define SH_STRIDE 72       // ushorts
#define SF_STRIDE 120      // ushorts fp16 F; sO overlays at 60 f32 (240B rows)

#define INV_SQRT3 0.5773502691896258f
#define INV_SQRT2 0.7071067811865476f
#define A_SCAL    0.22360679774997896f   // 1/sqrt(20)
#define A_VEC     0.20412414523193154f   // 1/sqrt(24)

typedef __bf16 bf16x8 __attribute__((ext_vector_type(8)));
typedef float  f32x4  __attribute__((ext_vector_type(4)));
typedef unsigned short u16x8 __attribute__((ext_vector_type(8)));
typedef unsigned short u16x4 __attribute__((ext_vector_type(4)));

__device__ __forceinline__ unsigned short f2bf(float f) {
    unsigned int u = __builtin_bit_cast(unsigned int, f);
    u += 0x7FFFu + ((u >> 16) & 1u);          // RNE
    return (unsigned short)(u >> 16);
}
__device__ __forceinline__ unsigned short f2h(float f) {
    __half h = __float2half(f);
    return __builtin_bit_cast(unsigned short, h);
}
__device__ __forceinline__ float h2f(unsigned short u) {
    __half h = __builtin_bit_cast(__half, u);
    return __half2float(h);
}

// ---- setup: W1T [n][64] + W2L lane-major fragment layout (weights only; accum via memset) ----
// W2L[o]: o = ((i*2+f)*64 + l)*8 + j ; lane l=(q*16+m); value = W2[k= f*32+q*8+j][n= i*16+m]
__global__ void k_setup(const float* __restrict__ w1, const float* __restrict__ b1,
                        const float* __restrict__ w2, const float* __restrict__ b2,
                        unsigned short* __restrict__ W1T, unsigned short* __restrict__ W2L)
{
    int o = blockIdx.x * 256 + threadIdx.x;
    if (o < 52 * 2 * 64 * 8) {
        int i = o >> 10;
        int rem = o & 1023;
        int f = rem >> 9;
        int rem2 = rem & 511;
        int l = rem2 >> 3, j = rem2 & 7;
        int mm = l & 15, qq = l >> 4;
        int k = f * 32 + qq * 8 + j;
        int n = i * 16 + mm;
        float v = (k < EF) ? w2[k * WN + n] : ((k == EF) ? b2[n] : 0.f);
        W2L[o] = f2bf(v);
    }
    if (o < EF * EF) { int k = o / EF, n = o - k * EF; W1T[n * 64 + k] = f2bf(w1[o]); }
    if (o < EF * 16) { int n = o >> 4, kk = EF + (o & 15); W1T[n * 64 + kk] = (kk == EF) ? f2bf(b1[n]) : (unsigned short)0; }
}

__global__ __launch_bounds__(NT, 2) void tp_fused(
    const float* __restrict__ node_attr,
    const float* __restrict__ edge_attr,
    const float* __restrict__ edge_sh,
    const int*   __restrict__ edge_index,
    const unsigned short* __restrict__ W1T,
    const unsigned short* __restrict__ W2L,
    float* __restrict__ accum,
    float* __restrict__ counts)
{
    // [sW2: 26624 B][sH: 18432 B] ; gather tile sG (128*56*4 = 28672 B) overlays sW2 + head of sH
    __shared__ __align__(16) unsigned char UB[26624 + EB * SH_STRIDE * 2];
    __shared__ __align__(16) unsigned short sF[EB * SF_STRIDE];  // 30720 B; sO overlays (stride 60 f32)
    __shared__ float sS1[EB][4];
    __shared__ int   sSrc[EB], sDst[EB];

    unsigned short* sW2 = (unsigned short*)UB;
    unsigned short* sH  = (unsigned short*)(UB + 26624);
    float*          sG  = (float*)UB;

    const int tid  = threadIdx.x;
    const int lane = tid & 63;
    const int wv   = tid >> 6;
    const int m    = lane & 15;
    const int quad = lane >> 4;
    const int e0   = blockIdx.x * EB;

    if (tid < EB) sSrc[tid] = edge_index[e0 + tid];
    else          sDst[tid - EB] = edge_index[NEDGE + e0 + tid - EB];
    __syncthreads();

    // ---- gather: 2 threads per edge, 7 float4 each ----
    {
        int ge = tid >> 1, gh = tid & 1;
        const float* nrow = node_attr + (size_t)sDst[ge] * IRR + gh * 28;
        float* g = sG + ge * 56 + gh * 28;
        #pragma unroll
        for (int j = 0; j < 7; j++) *(float4*)(g + j * 4) = *(const float4*)(nrow + j * 4);
    }
    __syncthreads();

    // ---- F features: 2 threads per edge (parts 0/1), fp16 stores ----
    {
        int fe = tid >> 1, part = tid & 1;
        const float* x = sG + fe * 56;
        float4 sh4 = *(const float4*)&edge_sh[(size_t)(e0 + fe) * 4];
        const float s0 = sh4.x, sx = sh4.y, sy = sh4.z, sz = sh4.w;
        unsigned short* F = sF + fe * SF_STRIDE;
        const float c0S = s0 * A_SCAL;
        const float c0V = s0 * A_VEC;
        const float cD3 = INV_SQRT3 * A_SCAL;
        const float cC2 = INV_SQRT2 * A_VEC;
        if (part == 0) {
            #pragma unroll
            for (int u = 0; u < 16; u++) {
                float x0e = x[u];
                F[u]      = f2h(x0e * c0S);
                F[20 + u] = f2h(x0e * A_VEC);
            }
            #pragma unroll
            for (int u = 0; u < 4; u++) {
                float a0 = x[16 + u*3], a1 = x[16 + u*3 + 1], a2 = x[16 + u*3 + 2]; // x1o
                float b0 = x[28 + u*3], b1 = x[28 + u*3 + 1], b2 = x[28 + u*3 + 2]; // x1e
                F[16 + u] = f2h((a0*sx + a1*sy + a2*sz) * cD3);           // dot_b
                F[36 + u*3 + 0] = f2h(a0 * c0V);                          // wB1
                F[36 + u*3 + 1] = f2h(a1 * c0V);
                F[36 + u*3 + 2] = f2h(a2 * c0V);
                F[48 + u*3 + 0] = f2h((b1*sz - b2*sy) * cC2);             // wC1: cross(x1e,s1)
                F[48 + u*3 + 1] = f2h((b2*sx - b0*sz) * cC2);
                F[48 + u*3 + 2] = f2h((b0*sy - b1*sx) * cC2);
            }
            sS1[fe][0] = sx; sS1[fe][1] = sy; sS1[fe][2] = sz;
        } else {
            #pragma unroll
            for (int u = 0; u < 16; u++) {
                float x0o = x[40 + u];
                F[84 + u]  = f2h(x0o * A_VEC);
                F[104 + u] = f2h(x0o * c0S);
            }
            #pragma unroll
            for (int u = 0; u < 4; u++) {
                float a0 = x[16 + u*3], a1 = x[16 + u*3 + 1], a2 = x[16 + u*3 + 2]; // x1o
                float b0 = x[28 + u*3], b1 = x[28 + u*3 + 1], b2 = x[28 + u*3 + 2]; // x1e
                F[100 + u] = f2h((b0*sx + b1*sy + b2*sz) * cD3);          // dot_c
                F[60 + u*3 + 0] = f2h((a1*sz - a2*sy) * cC2);             // wB1e: cross(x1o,s1)
                F[60 + u*3 + 1] = f2h((a2*sx - a0*sz) * cC2);
                F[60 + u*3 + 2] = f2h((a0*sy - a1*sx) * cC2);
                F[72 + u*3 + 0] = f2h(b0 * c0V);                          // wC1e
                F[72 + u*3 + 1] = f2h(b1 * c0V);
                F[72 + u*3 + 2] = f2h(b2 * c0V);
            }
        }
    }
    __syncthreads();    // sG dead after this point

    // ---- GEMM1 transposed: each wave covers 32 edges (2 row-tiles); writes sH ----
    #pragma unroll
    for (int rt = 0; rt < 2; rt++) {
        const int em = wv * 32 + rt * 16 + m;
        const float* arow = edge_attr + (size_t)(e0 + em) * EF;
        float av0[8], av1[8];
        {
            float4 p0 = *(const float4*)(arow + quad * 8);
            float4 p1 = *(const float4*)(arow + quad * 8 + 4);
            av0[0]=p0.x; av0[1]=p0.y; av0[2]=p0.z; av0[3]=p0.w;
            av0[4]=p1.x; av0[5]=p1.y; av0[6]=p1.z; av0[7]=p1.w;
        }
        if (quad < 2) {
            float4 p0 = *(const float4*)(arow + 32 + quad * 8);
            float4 p1 = *(const float4*)(arow + 32 + quad * 8 + 4);
            av1[0]=p0.x; av1[1]=p0.y; av1[2]=p0.z; av1[3]=p0.w;
            av1[4]=p1.x; av1[5]=p1.y; av1[6]=p1.z; av1[7]=p1.w;
        } else {
            #pragma unroll
            for (int j = 0; j < 8; j++) av1[j] = 0.f;
            if (quad == 2) av1[0] = 1.f;           // bias row k=48
        }
        u16x8 ub0, ub1;
        #pragma unroll
        for (int j = 0; j < 8; j++) { ub0[j] = f2bf(av0[j]); ub1[j] = f2bf(av1[j]); }
        bf16x8 hb0 = __builtin_bit_cast(bf16x8, ub0);
        bf16x8 hb1 = __builtin_bit_cast(bf16x8, ub1);

        #pragma unroll
        for (int nth = 0; nth < 3; nth++) {
            bf16x8 a0 = __builtin_bit_cast(bf16x8, *(const u16x8*)&W1T[(nth*16 + m)*64 + quad*8]);
            bf16x8 a1 = __builtin_bit_cast(bf16x8, *(const u16x8*)&W1T[(nth*16 + m)*64 + 32 + quad*8]);
            f32x4 c = {0.f, 0.f, 0.f, 0.f};
            c = __builtin_amdgcn_mfma_f32_16x16x32_bf16(a0, hb0, c, 0, 0, 0);
            c = __builtin_amdgcn_mfma_f32_16x16x32_bf16(a1, hb1, c, 0, 0, 0);
            u16x4 hp;
            #pragma unroll
            for (int r = 0; r < 4; r++) hp[r] = f2bf(fmaxf(c[r], 0.f));
            *(u16x4*)&sH[em * SH_STRIDE + nth*16 + quad*4] = hp;
        }
        if (quad == 3) {
            u16x4 b = {0x3F80, 0, 0, 0}, z = {0, 0, 0, 0};
            *(u16x4*)&sH[em * SH_STRIDE + 48] = b;
            *(u16x4*)&sH[em * SH_STRIDE + 52] = z;
            *(u16x4*)&sH[em * SH_STRIDE + 56] = z;
            *(u16x4*)&sH[em * SH_STRIDE + 60] = z;
        }
    }

    // ---- issue pass-0 staging loads early (L2 latency hides behind barrier + HB load) ----
    const uint4* w2src = (const uint4*)W2L;
    uint4 sreg[7];
    #pragma unroll
    for (int it = 0; it < 7; it++) {
        int idx = it * NT + tid;
        if (idx < PASS_U4) sreg[it] = w2src[idx];
    }
    __syncthreads();    // sH complete

    const int em0 = wv * 32 + m;
    const int em1 = em0 + 16;
    bf16x8 HB0 = __builtin_bit_cast(bf16x8, *(const u16x8*)&sH[em0 * SH_STRIDE + quad*8]);
    bf16x8 HB1 = __builtin_bit_cast(bf16x8, *(const u16x8*)&sH[em0 * SH_STRIDE + 32 + quad*8]);
    bf16x8 HB2 = __builtin_bit_cast(bf16x8, *(const u16x8*)&sH[em1 * SH_STRIDE + quad*8]);
    bf16x8 HB3 = __builtin_bit_cast(bf16x8, *(const u16x8*)&sH[em1 * SH_STRIDE + 32 + quad*8]);

    // ---- fused GEMM2 + consume: 4 passes, reg-double-buffered staging ----
    float oe[2][4]  = {{0,0,0,0},{0,0,0,0}};
    float oo[2][4]  = {{0,0,0,0},{0,0,0,0}};
    float sA[2][4]  = {{0,0,0,0},{0,0,0,0}};
    float sD[2][4]  = {{0,0,0,0},{0,0,0,0}};
    float t1o[2][12] = {};
    float t1e[2][12] = {};

    const unsigned short* Fm0 = sF + em0 * SF_STRIDE;
    const unsigned short* Fm1 = sF + em1 * SF_STRIDE;

    auto consume2 = [&](int nt, f32x4 c0, f32x4 c1) {
        if (nt < 20) {                          // o0e
            float f0 = h2f(Fm0[nt]), f1 = h2f(Fm1[nt]);
            #pragma unroll
            for (int r = 0; r < 4; r++) { oe[0][r] += f0 * c0[r]; oe[1][r] += f1 * c1[r]; }
        } else if (nt < 24) {                   // wA1 dot
            int o = 20 + (nt - 20)*4 + quad;
            float f0 = h2f(Fm0[o]), f1 = h2f(Fm1[o]);
            #pragma unroll
            for (int r = 0; r < 4; r++) { sA[0][r] += f0 * c0[r]; sA[1][r] += f1 * c1[r]; }
        } else if (nt < 26) {                   // wB1+wC1
            int u = (nt - 24)*4 + quad;
            #pragma unroll
            for (int i = 0; i < 3; i++) {
                float f0 = h2f(Fm0[36 + u*3 + i]), f1 = h2f(Fm1[36 + u*3 + i]);
                #pragma unroll
                for (int r = 0; r < 4; r++) { t1o[0][i*4+r] += f0 * c0[r]; t1o[1][i*4+r] += f1 * c1[r]; }
            }
        } else if (nt < 28) {                   // wB1e+wC1e
            int j = (nt - 26)*4 + quad;
            #pragma unroll
            for (int i = 0; i < 3; i++) {
                float f0 = h2f(Fm0[60 + j*3 + i]), f1 = h2f(Fm1[60 + j*3 + i]);
                #pragma unroll
                for (int r = 0; r < 4; r++) { t1e[0][i*4+r] += f0 * c0[r]; t1e[1][i*4+r] += f1 * c1[r]; }
            }
        } else if (nt < 32) {                   // wD1e dot
            int o = 84 + (nt - 28)*4 + quad;
            float f0 = h2f(Fm0[o]), f1 = h2f(Fm1[o]);
            #pragma unroll
            for (int r = 0; r < 4; r++) { sD[0][r] += f0 * c0[r]; sD[1][r] += f1 * c1[r]; }
        } else {                                // o0o
            float f0 = h2f(Fm0[68 + nt]), f1 = h2f(Fm1[68 + nt]);
            #pragma unroll
            for (int r = 0; r < 4; r++) { oo[0][r] += f0 * c0[r]; oo[1][r] += f1 * c1[r]; }
        }
    };

    uint4* w2dst = (uint4*)sW2;
    #pragma unroll 1
    for (int p = 0; p < 4; p++) {
        // write staged regs -> LDS
        #pragma unroll
        for (int it = 0; it < 7; it++) {
            int idx = it * NT + tid;
            if (idx < PASS_U4) w2dst[idx] = sreg[it];
        }
        __syncthreads();
        // fire loads for next pass (overlap with compute)
        if (p < 3) {
            const uint4* src = w2src + (p + 1) * PASS_U4;
            #pragma unroll
            for (int it = 0; it < 7; it++) {
                int idx = it * NT + tid;
                if (idx < PASS_U4) sreg[it] = src[idx];
            }
        }
        #pragma unroll
        for (int i = 0; i < TPP; i++) {
            u16x8 A = *(const u16x8*)&sW2[i * 1024 + lane * 8];
            u16x8 B = *(const u16x8*)&sW2[i * 1024 + 512 + lane * 8];
            f32x4 c0 = {0.f,0.f,0.f,0.f}, c1 = {0.f,0.f,0.f,0.f};
            c0 = __builtin_amdgcn_mfma_f32_16x16x32_bf16(__builtin_bit_cast(bf16x8, A), HB0, c0, 0, 0, 0);
            c0 = __builtin_amdgcn_mfma_f32_16x16x32_bf16(__builtin_bit_cast(bf16x8, B), HB1, c0, 0, 0, 0);
            c1 = __builtin_amdgcn_mfma_f32_16x16x32_bf16(__builtin_bit_cast(bf16x8, A), HB2, c1, 0, 0, 0);
            c1 = __builtin_amdgcn_mfma_f32_16x16x32_bf16(__builtin_bit_cast(bf16x8, B), HB3, c1, 0, 0, 0);
            consume2(p * TPP + i, c0, c1);
        }
        __syncthreads();   // all reads done before next pass overwrites sW2
    }

    // ---- cross-quad butterfly (o1o/o1e paths) ----
    #pragma unroll
    for (int g = 0; g < 2; g++) {
        #pragma unroll
        for (int r = 0; r < 4; r++) {
            sA[g][r] += __shfl_xor(sA[g][r], 16, 64);  sA[g][r] += __shfl_xor(sA[g][r], 32, 64);
            sD[g][r] += __shfl_xor(sD[g][r], 16, 64);  sD[g][r] += __shfl_xor(sD[g][r], 32, 64);
        }
        #pragma unroll
        for (int i = 0; i < 12; i++) {
            t1o[g][i] += __shfl_xor(t1o[g][i], 16, 64);  t1o[g][i] += __shfl_xor(t1o[g][i], 32, 64);
            t1e[g][i] += __shfl_xor(t1e[g][i], 16, 64);  t1e[g][i] += __shfl_xor(t1e[g][i], 32, 64);
        }
    }

    // ---- write per-edge outputs to sO (overlays sF; wave-private rows, no barrier needed) ----
    float* sO = (float*)sF;                    // stride 60 floats = 240B rows; f4 stores 16B-aligned
    #pragma unroll
    for (int g = 0; g < 2; g++) {
        const int em = em0 + g * 16;
        float4 v0; v0.x = oe[g][0]; v0.y = oe[g][1]; v0.z = oe[g][2]; v0.w = oe[g][3];
        float4 v1; v1.x = oo[g][0]; v1.y = oo[g][1]; v1.z = oo[g][2]; v1.w = oo[g][3];
        *(float4*)&sO[em * 60 + quad*4]      = v0;   // channels 0..15
        *(float4*)&sO[em * 60 + 40 + quad*4] = v1;   // channels 40..55
        if (quad == 0) {
            float s1x = sS1[em][0], s1y = sS1[em][1], s1z = sS1[em][2];
            #pragma unroll
            for (int r = 0; r < 4; r++) {
                sO[em * 60 + 16 + r*3 + 0] = sA[g][r] * s1x + t1o[g][0*4 + r];
                sO[em * 60 + 16 + r*3 + 1] = sA[g][r] * s1y + t1o[g][1*4 + r];
                sO[em * 60 + 16 + r*3 + 2] = sA[g][r] * s1z + t1o[g][2*4 + r];
            }
        } else if (quad == 1) {
            float s1x = sS1[em][0], s1y = sS1[em][1], s1z = sS1[em][2];
            #pragma unroll
            for (int r = 0; r < 4; r++) {
                sO[em * 60 + 28 + r*3 + 0] = sD[g][r] * s1x + t1e[g][0*4 + r];
                sO[em * 60 + 28 + r*3 + 1] = sD[g][r] * s1y + t1e[g][1*4 + r];
                sO[em * 60 + 28 + r*3 + 2] = sD[g][r] * s1z + t1e[g][2*4 + r];
            }
        }
    }
    __syncthreads();

    // ---- channel-major coalesced atomic scatter (line-merged) ----
    #pragma unroll
    for (int it = 0; it < 28; it++) {
        int idx = it * NT + tid;               // < 7168 = 128*56
        int e = idx / IRR, ch = idx - e * IRR;
        unsafeAtomicAdd(&accum[(size_t)sSrc[e] * IRR + ch], sO[e * 60 + ch]);
    }
    if (tid < EB) unsafeAtomicAdd(&counts[sSrc[tid]], 1.0f);
}

__global__ void tp_divide(const float* __restrict__ accum,
                          const float* __restrict__ counts,
                          float* __restrict__ out)
{
    int idx = blockIdx.x * blockDim.x + threadIdx.x;
    if (idx < NNODE * IRR) {
        out[idx] = accum[idx] / fmaxf(counts[idx / IRR], 1.0f);
    }
}

extern "C" void kernel_launch(void* const* d_in, const int* in_sizes, int n_in,
                              void* d_out, int out_size, void* d_ws, size_t ws_size,
                              hipStream_t stream) {
    const float* node_attr  = (const float*)d_in[0];
    const float* edge_attr  = (const float*)d_in[1];
    const float* edge_sh    = (const float*)d_in[2];
    const float* fc_w1      = (const float*)d_in[3];
    const float* fc_b1      = (const float*)d_in[4];
    const float* fc_w2      = (const float*)d_in[5];
    const float* fc_b2      = (const float*)d_in[6];
    const int*   edge_index = (const int*)d_in[7];

    float* accum  = (float*)d_ws;                              // 448000 f
    float* counts = accum + (size_t)NNODE * IRR;               // 8000 f
    unsigned short* W1T = (unsigned short*)(counts + NNODE);   // 48*64
    unsigned short* W2L = W1T + EF * 64;                       // 52*2*64*8 = 53248

    hipMemsetAsync(d_ws, 0, ((size_t)NNODE * IRR + NNODE) * sizeof(float), stream);

    k_setup<<<(52 * 2 * 64 * 8 + 255) / 256, 256, 0, stream>>>(
        fc_w1, fc_b1, fc_w2, fc_b2, W1T, W2L);

    tp_fused<<<NBLK, NT, 0, stream>>>(node_attr, edge_attr, edge_sh, edge_index,
                                      W1T, W2L, accum, counts);

    tp_divide<<<(NNODE * IRR + 255) / 256, 256, 0, stream>>>(accum, counts, (float*)d_out);
}

// Round 11
// 176.160 us; speedup vs baseline: 1.1934x; 1.1934x over previous
//
#include <hip/hip_runtime.h>
#include <hip/hip_fp16.h>

#define IRR    56
#define EF     48
#define WN     832
#define NEDGE  160000
#define NNODE  8000
#define NT     256
#define TE2    64                 // edges per task
#define NTASK  (NEDGE / TE2)      // 2500
#define GRID   512                // 2 flavors x 256

#define INV_SQRT3 0.5773502691896258f
#define INV_SQRT2 0.7071067811865476f
#define A_SCAL    0.22360679774997896f   // 1/sqrt(20)
#define A_VEC     0.20412414523193154f   // 1/sqrt(24)

typedef __bf16 bf16x8 __attribute__((ext_vector_type(8)));
typedef float  f32x4  __attribute__((ext_vector_type(4)));
typedef unsigned short u16x8 __attribute__((ext_vector_type(8)));
typedef unsigned short u16x4 __attribute__((ext_vector_type(4)));

__device__ __forceinline__ unsigned short f2bf(float f) {
    unsigned int u = __builtin_bit_cast(unsigned int, f);
    u += 0x7FFFu + ((u >> 16) & 1u);          // RNE
    return (unsigned short)(u >> 16);
}
__device__ __forceinline__ unsigned short f2h(float f) {
    __half h = __float2half(f);
    return __builtin_bit_cast(unsigned short, h);
}
__device__ __forceinline__ float h2f(unsigned short u) {
    __half h = __builtin_bit_cast(__half, u);
    return __half2float(h);
}

// ---- setup: W1T [n][64] + W2L lane-major fragment layout + src histogram ----
// W2L[o]: o = ((i*2+f)*64 + l)*8 + j ; lane l=(q*16+m); value = W2[k= f*32+q*8+j][n= i*16+m]
__global__ void k_setup(const float* __restrict__ w1, const float* __restrict__ b1,
                        const float* __restrict__ w2, const float* __restrict__ b2,
                        unsigned short* __restrict__ W1T, unsigned short* __restrict__ W2L,
                        const int* __restrict__ edge_index, int* __restrict__ hist)
{
    int o = blockIdx.x * 256 + threadIdx.x;
    if (o < 52 * 2 * 64 * 8) {
        int i = o >> 10;
        int rem = o & 1023;
        int f = rem >> 9;
        int rem2 = rem & 511;
        int l = rem2 >> 3, j = rem2 & 7;
        int mm = l & 15, qq = l >> 4;
        int k = f * 32 + qq * 8 + j;
        int n = i * 16 + mm;
        float v = (k < EF) ? w2[k * WN + n] : ((k == EF) ? b2[n] : 0.f);
        W2L[o] = f2bf(v);
    }
    if (o < EF * EF) { int k = o / EF, n = o - k * EF; W1T[n * 64 + k] = f2bf(w1[o]); }
    if (o < EF * 16) { int n = o >> 4, kk = EF + (o & 15); W1T[n * 64 + kk] = (kk == EF) ? f2bf(b1[n]) : (unsigned short)0; }
    if (o < NEDGE) atomicAdd(&hist[edge_index[o]], 1);   // src counts
}

__global__ __launch_bounds__(NT, 2) void tp_fused(
    const float* __restrict__ node_attr,
    const float* __restrict__ edge_attr,
    const float* __restrict__ edge_sh,
    const int*   __restrict__ edge_index,
    const int*   __restrict__ hist,
    const unsigned short* __restrict__ W1T,
    const unsigned short* __restrict__ W2L,
    float* __restrict__ out)
{
    __shared__ __align__(16) unsigned short sW2[26 * 1024];     // 53248 B resident W2 half
    __shared__ __align__(16) unsigned char  UGH[TE2 * 56 * 4];  // 14336 B: sG f32 -> sH u16 overlay
    __shared__ __align__(16) unsigned char  UFO[TE2 * 60 * 2];  // 7680 B:  sF u16 -> sO f32 (stride 28)
    __shared__ float sS1[TE2][4];
    __shared__ int   sSrc[TE2], sDst[TE2];
    __shared__ float sInv[TE2];

    float*          sG   = (float*)UGH;            // stride 56 f32 (224B rows, 16B-aligned)
    unsigned short* sH   = (unsigned short*)UGH;   // stride 72 u16 (144B rows, 16B-aligned)
    unsigned short* sF16 = (unsigned short*)UFO;   // stride 60 u16 (120B rows)
    float*          sO   = (float*)UFO;            // stride 28 f32 (112B rows, 16B-aligned)

    const int tid    = threadIdx.x;
    const int lane   = tid & 63;
    const int wv     = tid >> 6;
    const int m      = lane & 15;
    const int quad   = lane >> 4;
    const int em     = wv * 16 + m;                // task-local edge owned by this lane
    const int flavor = blockIdx.x & 1;             // 0: nt 0..25 -> ch 0..27 ; 1: nt 26..51 -> ch 28..55
    const int bid2   = blockIdx.x >> 1;

    // ---- stage resident W2 half ONCE (53248 B = 3328 uint4, 13/thread) ----
    {
        const uint4* src = (const uint4*)(W2L + (size_t)flavor * 26 * 1024);
        uint4* dst = (uint4*)sW2;
        #pragma unroll
        for (int it = 0; it < 13; it++) dst[it * NT + tid] = src[it * NT + tid];
    }

    for (int task = bid2; task < NTASK; task += 256) {
        const int e0 = task * TE2;
        __syncthreads();   // W2 staged (first iter) / prev scatter reads done
        if (tid < TE2)            sSrc[tid]       = edge_index[e0 + tid];
        else if (tid < 2 * TE2)   sDst[tid - TE2] = edge_index[NEDGE + e0 + tid - TE2];
        __syncthreads();

        // ---- gather node rows + inv(count) ----
        {
            const float* nrow = node_attr + (size_t)sDst[em] * IRR;
            float* g = sG + em * 56;
            #pragma unroll
            for (int t = 0; t < 3; t++) {
                int c = quad + t * 4;
                *(float4*)(g + c * 4) = *(const float4*)(nrow + c * 4);
            }
            if (quad < 2) { int c = 12 + quad; *(float4*)(g + c * 4) = *(const float4*)(nrow + c * 4); }
        }
        if (tid >= 128 && tid < 128 + TE2) {
            int e = tid - 128;
            sInv[e] = 1.0f / fmaxf((float)hist[sSrc[e]], 1.0f);
        }
        __syncthreads();

        // ---- F features (quad0 lanes), flavor-specific half, fp16 -> sF local stride 60 ----
        if (quad == 0) {
            const float* x = sG + em * 56;
            float4 sh4 = *(const float4*)&edge_sh[(size_t)(e0 + em) * 4];
            const float s0 = sh4.x, sx = sh4.y, sy = sh4.z, sz = sh4.w;
            unsigned short* F = sF16 + em * 60;
            const float c0S = s0 * A_SCAL;
            const float c0V = s0 * A_VEC;
            const float cD3 = INV_SQRT3 * A_SCAL;
            const float cC2 = INV_SQRT2 * A_VEC;
            if (flavor == 0) {
                #pragma unroll
                for (int u = 0; u < 16; u++) {
                    float x0e = x[u];
                    F[u]      = f2h(x0e * c0S);    // wA0
                    F[20 + u] = f2h(x0e * A_VEC);  // wA1
                }
                #pragma unroll
                for (int u = 0; u < 4; u++) {
                    float a0 = x[16 + u*3], a1 = x[16 + u*3 + 1], a2 = x[16 + u*3 + 2]; // x1o
                    float b0 = x[28 + u*3], b1 = x[28 + u*3 + 1], b2 = x[28 + u*3 + 2]; // x1e
                    F[16 + u] = f2h((a0*sx + a1*sy + a2*sz) * cD3);        // wB0 dot_b
                    F[36 + u*3 + 0] = f2h(a0 * c0V);                       // wB1
                    F[36 + u*3 + 1] = f2h(a1 * c0V);
                    F[36 + u*3 + 2] = f2h(a2 * c0V);
                    F[48 + u*3 + 0] = f2h((b1*sz - b2*sy) * cC2);          // wC1 cross(x1e,s1)
                    F[48 + u*3 + 1] = f2h((b2*sx - b0*sz) * cC2);
                    F[48 + u*3 + 2] = f2h((b0*sy - b1*sx) * cC2);
                }
            } else {
                #pragma unroll
                for (int u = 0; u < 4; u++) {
                    float a0 = x[16 + u*3], a1 = x[16 + u*3 + 1], a2 = x[16 + u*3 + 2]; // x1o
                    float b0 = x[28 + u*3], b1 = x[28 + u*3 + 1], b2 = x[28 + u*3 + 2]; // x1e
                    F[u*3 + 0]      = f2h((a1*sz - a2*sy) * cC2);          // wB1e cross(x1o,s1)  [g60..71]
                    F[u*3 + 1]      = f2h((a2*sx - a0*sz) * cC2);
                    F[u*3 + 2]      = f2h((a0*sy - a1*sx) * cC2);
                    F[12 + u*3 + 0] = f2h(b0 * c0V);                       // wC1e               [g72..83]
                    F[12 + u*3 + 1] = f2h(b1 * c0V);
                    F[12 + u*3 + 2] = f2h(b2 * c0V);
                    F[40 + u]       = f2h((b0*sx + b1*sy + b2*sz) * cD3);  // wC0o dot_c         [g100..103]
                }
                #pragma unroll
                for (int u = 0; u < 16; u++) {
                    float x0o = x[40 + u];
                    F[24 + u] = f2h(x0o * A_VEC);  // wD1e  [g84..99]
                    F[44 + u] = f2h(x0o * c0S);    // wD0o  [g104..119]
                }
            }
            sS1[em][0] = sx; sS1[em][1] = sy; sS1[em][2] = sz;
        }
        __syncthreads();   // sG reads done; sH may overlay

        // ---- GEMM1 transposed: lane holds H[e=em][hid] -> sH ----
        {
            const float* arow = edge_attr + (size_t)(e0 + em) * EF;
            float av0[8], av1[8];
            {
                float4 p0 = *(const float4*)(arow + quad * 8);
                float4 p1 = *(const float4*)(arow + quad * 8 + 4);
                av0[0]=p0.x; av0[1]=p0.y; av0[2]=p0.z; av0[3]=p0.w;
                av0[4]=p1.x; av0[5]=p1.y; av0[6]=p1.z; av0[7]=p1.w;
            }
            if (quad < 2) {
                float4 p0 = *(const float4*)(arow + 32 + quad * 8);
                float4 p1 = *(const float4*)(arow + 32 + quad * 8 + 4);
                av1[0]=p0.x; av1[1]=p0.y; av1[2]=p0.z; av1[3]=p0.w;
                av1[4]=p1.x; av1[5]=p1.y; av1[6]=p1.z; av1[7]=p1.w;
            } else {
                #pragma unroll
                for (int j = 0; j < 8; j++) av1[j] = 0.f;
                if (quad == 2) av1[0] = 1.f;           // bias row k=48
            }
            u16x8 ub0, ub1;
            #pragma unroll
            for (int j = 0; j < 8; j++) { ub0[j] = f2bf(av0[j]); ub1[j] = f2bf(av1[j]); }
            bf16x8 hb0 = __builtin_bit_cast(bf16x8, ub0);
            bf16x8 hb1 = __builtin_bit_cast(bf16x8, ub1);

            #pragma unroll
            for (int nth = 0; nth < 3; nth++) {
                bf16x8 a0 = __builtin_bit_cast(bf16x8, *(const u16x8*)&W1T[(nth*16 + m)*64 + quad*8]);
                bf16x8 a1 = __builtin_bit_cast(bf16x8, *(const u16x8*)&W1T[(nth*16 + m)*64 + 32 + quad*8]);
                f32x4 c = {0.f, 0.f, 0.f, 0.f};
                c = __builtin_amdgcn_mfma_f32_16x16x32_bf16(a0, hb0, c, 0, 0, 0);
                c = __builtin_amdgcn_mfma_f32_16x16x32_bf16(a1, hb1, c, 0, 0, 0);
                u16x4 hp;
                #pragma unroll
                for (int r = 0; r < 4; r++) hp[r] = f2bf(fmaxf(c[r], 0.f));
                *(u16x4*)&sH[em * 72 + nth*16 + quad*4] = hp;
            }
            if (quad == 3) {
                u16x4 b = {0x3F80, 0, 0, 0}, z = {0, 0, 0, 0};
                *(u16x4*)&sH[em * 72 + 48] = b;
                *(u16x4*)&sH[em * 72 + 52] = z;
                *(u16x4*)&sH[em * 72 + 56] = z;
                *(u16x4*)&sH[em * 72 + 60] = z;
            }
        }
        __syncthreads();

        bf16x8 HB0 = __builtin_bit_cast(bf16x8, *(const u16x8*)&sH[em * 72 + quad*8]);
        bf16x8 HB1 = __builtin_bit_cast(bf16x8, *(const u16x8*)&sH[em * 72 + 32 + quad*8]);

        const unsigned short* Fp = sF16 + em * 60;
        const float s1x = sS1[em][0], s1y = sS1[em][1], s1z = sS1[em][2];

        if (flavor == 0) {
            // ---- tiles nt 0..25: o0e (ch 0..15) + o1o (ch 16..27) ----
            float oe[4] = {0.f,0.f,0.f,0.f};
            float sA[4] = {0.f,0.f,0.f,0.f};
            float t1[12] = {0.f,0.f,0.f,0.f,0.f,0.f,0.f,0.f,0.f,0.f,0.f,0.f};
            #pragma unroll
            for (int i = 0; i < 26; i++) {
                u16x8 Af = *(const u16x8*)&sW2[i * 1024 + lane * 8];
                u16x8 Bf = *(const u16x8*)&sW2[i * 1024 + 512 + lane * 8];
                f32x4 c = {0.f,0.f,0.f,0.f};
                c = __builtin_amdgcn_mfma_f32_16x16x32_bf16(__builtin_bit_cast(bf16x8, Af), HB0, c, 0, 0, 0);
                c = __builtin_amdgcn_mfma_f32_16x16x32_bf16(__builtin_bit_cast(bf16x8, Bf), HB1, c, 0, 0, 0);
                if (i < 20) {
                    float f = h2f(Fp[i]);
                    #pragma unroll
                    for (int r = 0; r < 4; r++) oe[r] += f * c[r];
                } else if (i < 24) {
                    float f = h2f(Fp[20 + (i - 20)*4 + quad]);
                    #pragma unroll
                    for (int r = 0; r < 4; r++) sA[r] += f * c[r];
                } else {
                    int u = (i - 24)*4 + quad;
                    #pragma unroll
                    for (int i3 = 0; i3 < 3; i3++) {
                        float f = h2f(Fp[36 + u*3 + i3]);
                        #pragma unroll
                        for (int r = 0; r < 4; r++) t1[i3*4 + r] += f * c[r];
                    }
                }
            }
            #pragma unroll
            for (int r = 0; r < 4; r++) {
                sA[r] += __shfl_xor(sA[r], 16, 64);  sA[r] += __shfl_xor(sA[r], 32, 64);
            }
            #pragma unroll
            for (int i = 0; i < 12; i++) {
                t1[i] += __shfl_xor(t1[i], 16, 64);  t1[i] += __shfl_xor(t1[i], 32, 64);
            }
            __syncthreads();   // sF reads done block-wide before sO overlay
            float4 v0; v0.x = oe[0]; v0.y = oe[1]; v0.z = oe[2]; v0.w = oe[3];
            *(float4*)&sO[em * 28 + quad*4] = v0;                 // ch 0..15
            if (quad == 0) {
                #pragma unroll
                for (int r = 0; r < 4; r++) {
                    sO[em * 28 + 16 + r*3 + 0] = sA[r] * s1x + t1[0*4 + r];
                    sO[em * 28 + 16 + r*3 + 1] = sA[r] * s1y + t1[1*4 + r];
                    sO[em * 28 + 16 + r*3 + 2] = sA[r] * s1z + t1[2*4 + r];
                }
            }
        } else {
            // ---- tiles nt 26..51: o1e (ch 28..39) + o0o (ch 40..55) ----
            float sD[4] = {0.f,0.f,0.f,0.f};
            float t1[12] = {0.f,0.f,0.f,0.f,0.f,0.f,0.f,0.f,0.f,0.f,0.f,0.f};
            float oo[4] = {0.f,0.f,0.f,0.f};
            #pragma unroll
            for (int i = 0; i < 26; i++) {
                u16x8 Af = *(const u16x8*)&sW2[i * 1024 + lane * 8];
                u16x8 Bf = *(const u16x8*)&sW2[i * 1024 + 512 + lane * 8];
                f32x4 c = {0.f,0.f,0.f,0.f};
                c = __builtin_amdgcn_mfma_f32_16x16x32_bf16(__builtin_bit_cast(bf16x8, Af), HB0, c, 0, 0, 0);
                c = __builtin_amdgcn_mfma_f32_16x16x32_bf16(__builtin_bit_cast(bf16x8, Bf), HB1, c, 0, 0, 0);
                if (i < 2) {
                    int j = i*4 + quad;
                    #pragma unroll
                    for (int i3 = 0; i3 < 3; i3++) {
                        float f = h2f(Fp[j*3 + i3]);
                        #pragma unroll
                        for (int r = 0; r < 4; r++) t1[i3*4 + r] += f * c[r];
                    }
                } else if (i < 6) {
                    float f = h2f(Fp[24 + (i - 2)*4 + quad]);
                    #pragma unroll
                    for (int r = 0; r < 4; r++) sD[r] += f * c[r];
                } else {
                    float f = h2f(Fp[40 + (i - 6)]);
                    #pragma unroll
                    for (int r = 0; r < 4; r++) oo[r] += f * c[r];
                }
            }
            #pragma unroll
            for (int r = 0; r < 4; r++) {
                sD[r] += __shfl_xor(sD[r], 16, 64);  sD[r] += __shfl_xor(sD[r], 32, 64);
            }
            #pragma unroll
            for (int i = 0; i < 12; i++) {
                t1[i] += __shfl_xor(t1[i], 16, 64);  t1[i] += __shfl_xor(t1[i], 32, 64);
            }
            __syncthreads();   // sF reads done block-wide before sO overlay
            float4 v1; v1.x = oo[0]; v1.y = oo[1]; v1.z = oo[2]; v1.w = oo[3];
            *(float4*)&sO[em * 28 + 12 + quad*4] = v1;            // local ch 12..27 -> global 40..55
            if (quad == 0) {
                #pragma unroll
                for (int r = 0; r < 4; r++) {                     // local ch 0..11 -> global 28..39
                    sO[em * 28 + r*3 + 0] = sD[r] * s1x + t1[0*4 + r];
                    sO[em * 28 + r*3 + 1] = sD[r] * s1y + t1[1*4 + r];
                    sO[em * 28 + r*3 + 2] = sD[r] * s1z + t1[2*4 + r];
                }
            }
        }
        __syncthreads();

        // ---- pre-scaled channel-major atomic scatter directly into d_out ----
        #pragma unroll
        for (int it = 0; it < 7; it++) {
            int idx = it * NT + tid;           // < 1792 = 64*28
            int e = idx / 28, ch = idx - e * 28;
            unsafeAtomicAdd(&out[(size_t)sSrc[e] * IRR + flavor * 28 + ch],
                            sO[e * 28 + ch] * sInv[e]);
        }
    }
}

extern "C" void kernel_launch(void* const* d_in, const int* in_sizes, int n_in,
                              void* d_out, int out_size, void* d_ws, size_t ws_size,
                              hipStream_t stream) {
    const float* node_attr  = (const float*)d_in[0];
    const float* edge_attr  = (const float*)d_in[1];
    const float* edge_sh    = (const float*)d_in[2];
    const float* fc_w1      = (const float*)d_in[3];
    const float* fc_b1      = (const float*)d_in[4];
    const float* fc_w2      = (const float*)d_in[5];
    const float* fc_b2      = (const float*)d_in[6];
    const int*   edge_index = (const int*)d_in[7];

    int* hist = (int*)d_ws;                                    // 8000 ints
    unsigned short* W1T = (unsigned short*)(hist + NNODE);     // 48*64
    unsigned short* W2L = W1T + EF * 64;                       // 52*2*64*8 = 53248

    hipMemsetAsync(hist, 0, NNODE * sizeof(int), stream);
    hipMemsetAsync(d_out, 0, (size_t)out_size * sizeof(float), stream);

    k_setup<<<(NEDGE + 255) / 256, 256, 0, stream>>>(
        fc_w1, fc_b1, fc_w2, fc_b2, W1T, W2L, edge_index, hist);

    tp_fused<<<GRID, NT, 0, stream>>>(node_attr, edge_attr, edge_sh, edge_index,
                                      hist, W1T, W2L, (float*)d_out);
}